// Round 1
// baseline (3067.186 us; speedup 1.0000x reference)
//
#include <hip/hip_runtime.h>
#include <hip/hip_bf16.h>
#include <math.h>

// ---------------------------------------------------------------------------
// LinearCrossEntropy via MX-fp8 MFMA (16x16x128 f8f6f4, uniform HW scales).
// R5: GEMM restructured to the 256x256 8-phase double-buffered pipeline
//   (T1 XCD swizzle + T2 fp8 XOR LDS swizzle + T3/T4 8-phase counted-vmcnt
//    + T5 setprio), 512 threads / 8 waves, 128 KiB LDS, fused LSE epilogue.
// Dispatches: memset, cast_all, gemm, lse_finish, final_scalar.
// ---------------------------------------------------------------------------

#define BM 256
#define BN 256
#define BKB 128  // K elements (= bytes, fp8) per K-tile

typedef int   i32x8 __attribute__((ext_vector_type(8)));
typedef float f32x4 __attribute__((ext_vector_type(4)));

__device__ __forceinline__ void load_lds16(const void* g, void* l) {
    __builtin_amdgcn_global_load_lds(
        (const __attribute__((address_space(1))) void*)g,
        (__attribute__((address_space(3))) void*)l, 16, 0, 0);
}

// ---- fp8 e4m3fn conversion -------------------------------------------------
__device__ __forceinline__ unsigned char f2e4m3_sw(float x) {
    unsigned u = __float_as_uint(x);
    unsigned s = (u >> 24) & 0x80;
    float ax = __uint_as_float(u & 0x7fffffff);
    if (ax != ax) return (unsigned char)(s | 0x7f);
    if (ax >= 448.f) return (unsigned char)(s | 0x7e);
    if (ax < 0.0009765625f) return (unsigned char)s;      // < 2^-10 -> 0
    if (ax < 0.015625f) {                                 // subnormal, ulp 2^-9
        int n = (int)rintf(ax * 512.f);
        return (unsigned char)(s | n);
    }
    int e = (int)((u >> 23) & 0xff) - 127;
    unsigned m = u & 0x7fffff;
    unsigned keep = m >> 20, rest = m & 0xfffff;
    if (rest > 0x80000u || (rest == 0x80000u && (keep & 1))) keep++;
    if (keep == 8) { keep = 0; e++; if (e > 8) return (unsigned char)(s | 0x7e); }
    return (unsigned char)(s | ((e + 7) << 3) | keep);
}

__device__ __forceinline__ unsigned int pk4_fp8(float a, float b, float c, float d) {
#if __has_builtin(__builtin_amdgcn_cvt_pk_fp8_f32)
    int v = __builtin_amdgcn_cvt_pk_fp8_f32(a, b, 0, false);  // bytes 0,1
    v = __builtin_amdgcn_cvt_pk_fp8_f32(c, d, v, true);       // bytes 2,3
    return (unsigned int)v;
#else
    return (unsigned int)f2e4m3_sw(a) | ((unsigned int)f2e4m3_sw(b) << 8) |
           ((unsigned int)f2e4m3_sw(c) << 16) | ((unsigned int)f2e4m3_sw(d) << 24);
#endif
}

// Combined cast: [0,ne) from e (scale 1), [ne, ne+ncd) from c (scale 16,
// zero-fill past ncs). All boundaries multiples of 8.
__global__ void cast_all_fp8(const float* __restrict__ e,
                             const float* __restrict__ c,
                             unsigned char* __restrict__ e_f8,
                             unsigned char* __restrict__ c_f8,
                             long ne, long ncs, long ncd) {
    long i8 = ((long)blockIdx.x * blockDim.x + threadIdx.x) * 8;
    if (i8 >= ne + ncd) return;
    const float* src;
    unsigned char* dst;
    float scale;
    bool zero = false;
    if (i8 < ne) {
        src = e + i8; dst = e_f8 + i8; scale = 1.0f;
    } else {
        long j8 = i8 - ne;
        dst = c_f8 + j8; scale = 16.0f;
        src = c + j8;
        zero = (j8 + 7 >= ncs);
    }
    uint2 o;
    if (!zero) {
        float4 v0 = *(const float4*)(src);
        float4 v1 = *(const float4*)(src + 4);
        o.x = pk4_fp8(v0.x * scale, v0.y * scale, v0.z * scale, v0.w * scale);
        o.y = pk4_fp8(v1.x * scale, v1.y * scale, v1.z * scale, v1.w * scale);
    } else {
        o.x = o.y = 0u;
    }
    *(uint2*)dst = o;
}

// ---- GEMM 256x256, 8-phase double-buffered pipeline, fused LSE epilogue ----
// E: [N][D] fp8, C: [Vpad][D] fp8 (zero-pad rows).
// LDS: A 2x(256x128B)=64KB at [0,65536), B same at [65536,131072).
// Row r chunk c (16B) stored at chunk position c^(r&7) (XOR swizzle), achieved
// by pre-swizzling the per-lane GLOBAL source address (linear LDS dest).

#define VM4 asm volatile("s_waitcnt vmcnt(4)" ::: "memory")
#define VM0 asm volatile("s_waitcnt vmcnt(0)" ::: "memory")
#define NOPW ((void)0)

#define STG_A(k, h, b) do {                                                   \
    const unsigned char* _s = gA + (size_t)(h) * 128 * D + (size_t)(k) * 128; \
    load_lds16(_s,          lA + (b) * 32768 + (h) * 16384);                  \
    load_lds16(_s + rowD64, lA + (b) * 32768 + (h) * 16384 + 8192);           \
} while (0)

#define STG_B(k, h, b) do {                                                   \
    const unsigned char* _s = gB + (size_t)(h) * 128 * D + (size_t)(k) * 128; \
    load_lds16(_s,          lB + (b) * 32768 + (h) * 16384);                  \
    load_lds16(_s + rowD64, lB + (b) * 32768 + (h) * 16384 + 8192);           \
} while (0)

#define LDA_FRAG(dst, ti, b) do {                                             \
    const unsigned char* _pr = ldsA + (b) * 32768 + (wr0 + (ti) * 16 + lm) * 128; \
    int4 _lo = *(const int4*)(_pr + c0);                                      \
    int4 _hi = *(const int4*)(_pr + c1);                                      \
    dst = (i32x8){_lo.x, _lo.y, _lo.z, _lo.w, _hi.x, _hi.y, _hi.z, _hi.w};    \
} while (0)

#define LDB_FRAG(dst, tj, b) do {                                             \
    const unsigned char* _pr = ldsB + (b) * 32768 + (wc0 + (tj) * 16 + lm) * 128; \
    int4 _lo = *(const int4*)(_pr + c0);                                      \
    int4 _hi = *(const int4*)(_pr + c1);                                      \
    dst = (i32x8){_lo.x, _lo.y, _lo.z, _lo.w, _hi.x, _hi.y, _hi.z, _hi.w};    \
} while (0)

#define MFMA1(a, bfr, c) __builtin_amdgcn_mfma_scale_f32_16x16x128_f8f6f4(    \
    (a), (bfr), (c), 0, 0, 0, sA, 0, sB)

// One phase: ds-read A-quarter (and all B frags if LOADB), issue one half-tile
// stage, optional vmcnt checkpoint, barrier, lgkm drain, 8 MFMAs, barrier.
#define PHASE(q, b, LOADB, STAGE, WAITV) do {                                 \
    i32x8 _a0, _a1;                                                           \
    LDA_FRAG(_a0, 2 * (q), b);                                                \
    LDA_FRAG(_a1, 2 * (q) + 1, b);                                            \
    if (LOADB) {                                                              \
        LDB_FRAG(bf0, 0, b); LDB_FRAG(bf1, 1, b);                             \
        LDB_FRAG(bf2, 2, b); LDB_FRAG(bf3, 3, b);                             \
    }                                                                         \
    STAGE;                                                                    \
    WAITV;                                                                    \
    __builtin_amdgcn_s_barrier();                                             \
    asm volatile("s_waitcnt lgkmcnt(0)" ::: "memory");                        \
    __builtin_amdgcn_sched_barrier(0);                                        \
    __builtin_amdgcn_s_setprio(1);                                            \
    acc[2 * (q)][0]     = MFMA1(_a0, bf0, acc[2 * (q)][0]);                   \
    acc[2 * (q)][1]     = MFMA1(_a0, bf1, acc[2 * (q)][1]);                   \
    acc[2 * (q)][2]     = MFMA1(_a0, bf2, acc[2 * (q)][2]);                   \
    acc[2 * (q)][3]     = MFMA1(_a0, bf3, acc[2 * (q)][3]);                   \
    acc[2 * (q) + 1][0] = MFMA1(_a1, bf0, acc[2 * (q) + 1][0]);               \
    acc[2 * (q) + 1][1] = MFMA1(_a1, bf1, acc[2 * (q) + 1][1]);               \
    acc[2 * (q) + 1][2] = MFMA1(_a1, bf2, acc[2 * (q) + 1][2]);               \
    acc[2 * (q) + 1][3] = MFMA1(_a1, bf3, acc[2 * (q) + 1][3]);               \
    __builtin_amdgcn_s_setprio(0);                                            \
    __builtin_amdgcn_sched_barrier(0);                                        \
    __builtin_amdgcn_s_barrier();                                             \
    asm volatile("" ::: "memory");                                            \
} while (0)

__global__ __launch_bounds__(512, 2)
void gemm_lse_partial(const unsigned char* __restrict__ E,
                      const unsigned char* __restrict__ C,
                      const float* __restrict__ bias,
                      const int* __restrict__ targets,
                      float* __restrict__ row_sum,
                      float* __restrict__ tgt,
                      int N, int D, int V, int mtiles) {
    __shared__ unsigned char smem[131072];
    unsigned char* ldsA = smem;
    unsigned char* ldsB = smem + 65536;

    const int t_ = threadIdx.x;
    const int w  = t_ >> 6;
    const int l  = t_ & 63;
    const int quad = l >> 4;
    const int lm = l & 15;
    const int wr0 = (w >> 2) * 128;   // 2 row-groups of 128
    const int wc0 = (w & 3) * 64;     // 4 col-groups of 64
    const int c0 = ((quad << 1) ^ (lm & 7)) << 4;
    const int c1 = c0 ^ 16;

    // XCD-bijective block swizzle (nwg % 8 == 0 here; identity fallback else)
    const int nwg = (int)gridDim.x;
    int swz;
    if (nwg & 7) swz = (int)blockIdx.x;
    else         swz = ((int)blockIdx.x & 7) * (nwg >> 3) + ((int)blockIdx.x >> 3);
    const int mt = swz % mtiles;
    const int vt = swz / mtiles;
    const int m0 = mt * BM;
    const int v0 = vt * BN;

    // staging map: thread t -> row sr = t>>3, stored chunk t&7 (LDS linear per
    // wave: base + lane*16). Global chunk pre-swizzled: gc = (t&7) ^ (sr&7).
    const int sr = t_ >> 3;                    // 0..63
    const int gc = (t_ & 7) ^ (sr & 7);
    const unsigned char* gA = E + (size_t)(m0 + sr) * D + gc * 16;
    const unsigned char* gB = C + (size_t)(v0 + sr) * D + gc * 16;
    unsigned char* lA = ldsA + w * 1024;       // wave-uniform LDS base
    unsigned char* lB = ldsB + w * 1024;
    const size_t rowD64 = (size_t)64 * D;

    f32x4 acc[8][4] = {};
    i32x8 bf0, bf1, bf2, bf3;
    const int sA = 127;  // e8m0 2^0   (E)
    const int sB = 123;  // e8m0 2^-4  (undoes *16 in cast of C)
    const int KT  = D / BKB;   // 8 K-tiles
    const int NIT = KT / 2;    // 4 iterations, 2 K-tiles each

    // ---- prologue: K-tile 0 (A+B) into buf0, B of K-tile 1 into buf1 -------
    STG_A(0, 0, 0); STG_A(0, 1, 0);
    STG_B(0, 0, 0); STG_B(0, 1, 0);
    STG_B(1, 0, 1); STG_B(1, 1, 1);
    VM4;                                       // A(0),B(0) landed; B(1) in flight
    __builtin_amdgcn_s_barrier();
    asm volatile("" ::: "memory");

    // ---- main loop: iter t computes K-tiles 2t (buf0) and 2t+1 (buf1) ------
    // Stage stream: p1,2: A(2t+1); p3,4: B(2t+2); p5,6: A(2t+2); p7,8: B(2t+3).
    // Checkpoints vmcnt(4) at p4 (A(2t+1)+older landed) and p8 (A/B(2t+2)
    // landed). Last iter: only A(2t+1) staged; vmcnt(0) at p4.
    for (int t = 0; t < NIT; ++t) {
        const int k0 = 2 * t;
        const bool full = (t < NIT - 1);
        PHASE(0, 0, 1, STG_A(k0 + 1, 0, 1), NOPW);
        PHASE(1, 0, 0, STG_A(k0 + 1, 1, 1), NOPW);
        PHASE(2, 0, 0, if (full) STG_B(k0 + 2, 0, 0), NOPW);
        PHASE(3, 0, 0, if (full) STG_B(k0 + 2, 1, 0), if (full) VM4; else VM0);
        PHASE(0, 1, 1, if (full) STG_A(k0 + 2, 0, 0), NOPW);
        PHASE(1, 1, 0, if (full) STG_A(k0 + 2, 1, 0), NOPW);
        PHASE(2, 1, 0, if (full) STG_B(k0 + 3, 0, 1), NOPW);
        PHASE(3, 1, 0, if (full) STG_B(k0 + 3, 1, 1), if (full) VM4; else VM0);
    }

    // ---- epilogue: bias + exp + target extraction + per-row sums -----------
    // acc[ti][tj][r] -> row = wr0+ti*16+quad*4+r, col = wc0+tj*16+lm
    __syncthreads();                 // all MFMA/LDS done; re-alias tile LDS
    float* red = (float*)smem;       // [4 col-wave-groups][256 rows]

    float bv[4];
#pragma unroll
    for (int tj = 0; tj < 4; tj++) {
        int col = v0 + wc0 + tj * 16 + lm;
        bv[tj] = (col < V) ? bias[col] : -INFINITY;
    }
#pragma unroll
    for (int ti = 0; ti < 8; ti++) {
#pragma unroll
        for (int r = 0; r < 4; r++) {
            const int rl = wr0 + ti * 16 + quad * 4 + r;
            const int tl = targets[m0 + rl] - v0 - wc0;
            float s = 0.f;
#pragma unroll
            for (int tj = 0; tj < 4; tj++) {
                float v = acc[ti][tj][r] + bv[tj];   // pad col: exp(-inf)=0
                s += __expf(v);
                if (tj * 16 + lm == tl) tgt[m0 + rl] = v;
            }
#pragma unroll
            for (int off = 1; off < 16; off <<= 1)
                s += __shfl_xor(s, off, 64);
            if (lm == 0) red[(w & 3) * 256 + rl] = s;
        }
    }
    __syncthreads();
    if (t_ < 256)
        atomicAdd(&row_sum[m0 + t_],
                  red[t_] + red[256 + t_] + red[512 + t_] + red[768 + t_]);
}

// Finish: nll per row, block-reduce, atomic accumulate (sum, count).
__global__ void lse_finish(const float* __restrict__ row_sum,
                           const float* __restrict__ tgt,
                           const int* __restrict__ targets,
                           float* __restrict__ gacc, int N) {
    __shared__ float sred[8];
    int r = blockIdx.x * 256 + threadIdx.x;
    float nll = 0.f, cnt = 0.f;
    if (r < N) {
        int tg = targets[r];
        if (tg != -100) { nll = logf(row_sum[r]) - tgt[r]; cnt = 1.f; }
    }
#pragma unroll
    for (int off = 32; off; off >>= 1) {
        nll += __shfl_xor(nll, off, 64);
        cnt += __shfl_xor(cnt, off, 64);
    }
    int w = threadIdx.x >> 6, l = threadIdx.x & 63;
    if (l == 0) { sred[w] = nll; sred[4 + w] = cnt; }
    __syncthreads();
    if (threadIdx.x == 0) {
        atomicAdd(gacc, sred[0] + sred[1] + sred[2] + sred[3]);
        atomicAdd(gacc + 1, sred[4] + sred[5] + sred[6] + sred[7]);
    }
}

__global__ void final_scalar(const float* __restrict__ gacc, float* __restrict__ out) {
    out[0] = gacc[0] / fmaxf(gacc[1], 1.f);
}

extern "C" void kernel_launch(void* const* d_in, const int* in_sizes, int n_in,
                              void* d_out, int out_size, void* d_ws, size_t ws_size,
                              hipStream_t stream) {
    const float* e       = (const float*)d_in[0];
    const float* c       = (const float*)d_in[1];
    const int*   targets = (const int*)d_in[2];
    const float* bias    = (const float*)d_in[3];
    float* out = (float*)d_out;

    const int N = in_sizes[2];            // 8192
    const int V = in_sizes[3];            // 50257
    const int D = in_sizes[0] / N;        // 1024
    const int mtiles = N / BM;            // 32
    const int vtiles = (V + BN - 1) / BN; // 197
    const long Vpad = (long)vtiles * BN;  // 50432

    char* ws = (char*)d_ws;
    size_t off = 0;
    auto alloc = [&](size_t bytes) {
        void* p = ws + off;
        off += (bytes + 255) & ~(size_t)255;
        return p;
    };
    unsigned char* e_f8 = (unsigned char*)alloc((size_t)N * D);
    unsigned char* c_f8 = (unsigned char*)alloc((size_t)Vpad * D);
    float* row_sum = (float*)alloc((size_t)N * 4);   // zeroed below
    float* gacc    = (float*)alloc(8);               // adjacent to row_sum
    float* tgt     = (float*)alloc((size_t)N * 4);

    // one memset covers row_sum (N*4, 256-rounded) + gacc
    hipMemsetAsync(row_sum, 0, (size_t)N * 4 + 256 + 8, stream);

    const long ne  = (long)N * D;
    const long ncs = (long)V * D;
    const long ncd = Vpad * D;
    const long tot8 = (ne + ncd) / 8;
    cast_all_fp8<<<(int)((tot8 + 255) / 256), 256, 0, stream>>>(
        e, c, e_f8, c_f8, ne, ncs, ncd);

    const int nblk = mtiles * vtiles;     // 6304 (divisible by 8)
    gemm_lse_partial<<<nblk, 512, 0, stream>>>(e_f8, c_f8, bias, targets,
                                               row_sum, tgt, N, D, V, mtiles);

    lse_finish<<<(N + 255) / 256, 256, 0, stream>>>(row_sum, tgt, targets, gacc, N);
    final_scalar<<<1, 1, 0, stream>>>(gacc, out);
}

// Round 2
// 3056.890 us; speedup vs baseline: 1.0034x; 1.0034x over previous
//
#include <hip/hip_runtime.h>
#include <hip/hip_bf16.h>
#include <math.h>

// ---------------------------------------------------------------------------
// LinearCrossEntropy via MX-fp8 MFMA (16x16x128 f8f6f4, uniform HW scales).
// R6: same 256x256 8-phase double-buffered pipeline as R5, but
//   __launch_bounds__(512, 1): R5's (512,2) capped the unified VGPR+AGPR file
//   at 256/wave -> ~60-reg spill (5.7 GB scratch writes/dispatch, MfmaUtil 6%).
//   LDS (128 KiB) already limits to 1 block/CU, so the cap change costs no
//   occupancy.
// Dispatches: memset, cast_all, gemm, lse_finish, final_scalar.
// ---------------------------------------------------------------------------

#define BM 256
#define BN 256
#define BKB 128  // K elements (= bytes, fp8) per K-tile

typedef int   i32x8 __attribute__((ext_vector_type(8)));
typedef float f32x4 __attribute__((ext_vector_type(4)));

__device__ __forceinline__ void load_lds16(const void* g, void* l) {
    __builtin_amdgcn_global_load_lds(
        (const __attribute__((address_space(1))) void*)g,
        (__attribute__((address_space(3))) void*)l, 16, 0, 0);
}

// ---- fp8 e4m3fn conversion -------------------------------------------------
__device__ __forceinline__ unsigned char f2e4m3_sw(float x) {
    unsigned u = __float_as_uint(x);
    unsigned s = (u >> 24) & 0x80;
    float ax = __uint_as_float(u & 0x7fffffff);
    if (ax != ax) return (unsigned char)(s | 0x7f);
    if (ax >= 448.f) return (unsigned char)(s | 0x7e);
    if (ax < 0.0009765625f) return (unsigned char)s;      // < 2^-10 -> 0
    if (ax < 0.015625f) {                                 // subnormal, ulp 2^-9
        int n = (int)rintf(ax * 512.f);
        return (unsigned char)(s | n);
    }
    int e = (int)((u >> 23) & 0xff) - 127;
    unsigned m = u & 0x7fffff;
    unsigned keep = m >> 20, rest = m & 0xfffff;
    if (rest > 0x80000u || (rest == 0x80000u && (keep & 1))) keep++;
    if (keep == 8) { keep = 0; e++; if (e > 8) return (unsigned char)(s | 0x7e); }
    return (unsigned char)(s | ((e + 7) << 3) | keep);
}

__device__ __forceinline__ unsigned int pk4_fp8(float a, float b, float c, float d) {
#if __has_builtin(__builtin_amdgcn_cvt_pk_fp8_f32)
    int v = __builtin_amdgcn_cvt_pk_fp8_f32(a, b, 0, false);  // bytes 0,1
    v = __builtin_amdgcn_cvt_pk_fp8_f32(c, d, v, true);       // bytes 2,3
    return (unsigned int)v;
#else
    return (unsigned int)f2e4m3_sw(a) | ((unsigned int)f2e4m3_sw(b) << 8) |
           ((unsigned int)f2e4m3_sw(c) << 16) | ((unsigned int)f2e4m3_sw(d) << 24);
#endif
}

// Combined cast: [0,ne) from e (scale 1), [ne, ne+ncd) from c (scale 16,
// zero-fill past ncs). All boundaries multiples of 8.
__global__ void cast_all_fp8(const float* __restrict__ e,
                             const float* __restrict__ c,
                             unsigned char* __restrict__ e_f8,
                             unsigned char* __restrict__ c_f8,
                             long ne, long ncs, long ncd) {
    long i8 = ((long)blockIdx.x * blockDim.x + threadIdx.x) * 8;
    if (i8 >= ne + ncd) return;
    const float* src;
    unsigned char* dst;
    float scale;
    bool zero = false;
    if (i8 < ne) {
        src = e + i8; dst = e_f8 + i8; scale = 1.0f;
    } else {
        long j8 = i8 - ne;
        dst = c_f8 + j8; scale = 16.0f;
        src = c + j8;
        zero = (j8 + 7 >= ncs);
    }
    uint2 o;
    if (!zero) {
        float4 v0 = *(const float4*)(src);
        float4 v1 = *(const float4*)(src + 4);
        o.x = pk4_fp8(v0.x * scale, v0.y * scale, v0.z * scale, v0.w * scale);
        o.y = pk4_fp8(v1.x * scale, v1.y * scale, v1.z * scale, v1.w * scale);
    } else {
        o.x = o.y = 0u;
    }
    *(uint2*)dst = o;
}

// ---- GEMM 256x256, 8-phase double-buffered pipeline, fused LSE epilogue ----
// E: [N][D] fp8, C: [Vpad][D] fp8 (zero-pad rows).
// LDS: A 2x(256x128B)=64KB at [0,65536), B same at [65536,131072).
// Row r chunk c (16B) stored at chunk position c^(r&7) (XOR swizzle), achieved
// by pre-swizzling the per-lane GLOBAL source address (linear LDS dest).

#define VM4 asm volatile("s_waitcnt vmcnt(4)" ::: "memory")
#define VM0 asm volatile("s_waitcnt vmcnt(0)" ::: "memory")
#define NOPW ((void)0)

#define STG_A(k, h, b) do {                                                   \
    const unsigned char* _s = gA + (size_t)(h) * 128 * D + (size_t)(k) * 128; \
    load_lds16(_s,          lA + (b) * 32768 + (h) * 16384);                  \
    load_lds16(_s + rowD64, lA + (b) * 32768 + (h) * 16384 + 8192);           \
} while (0)

#define STG_B(k, h, b) do {                                                   \
    const unsigned char* _s = gB + (size_t)(h) * 128 * D + (size_t)(k) * 128; \
    load_lds16(_s,          lB + (b) * 32768 + (h) * 16384);                  \
    load_lds16(_s + rowD64, lB + (b) * 32768 + (h) * 16384 + 8192);           \
} while (0)

#define LDA_FRAG(dst, ti, b) do {                                             \
    const unsigned char* _pr = ldsA + (b) * 32768 + (wr0 + (ti) * 16 + lm) * 128; \
    int4 _lo = *(const int4*)(_pr + c0);                                      \
    int4 _hi = *(const int4*)(_pr + c1);                                      \
    dst = (i32x8){_lo.x, _lo.y, _lo.z, _lo.w, _hi.x, _hi.y, _hi.z, _hi.w};    \
} while (0)

#define LDB_FRAG(dst, tj, b) do {                                             \
    const unsigned char* _pr = ldsB + (b) * 32768 + (wc0 + (tj) * 16 + lm) * 128; \
    int4 _lo = *(const int4*)(_pr + c0);                                      \
    int4 _hi = *(const int4*)(_pr + c1);                                      \
    dst = (i32x8){_lo.x, _lo.y, _lo.z, _lo.w, _hi.x, _hi.y, _hi.z, _hi.w};    \
} while (0)

#define MFMA1(a, bfr, c) __builtin_amdgcn_mfma_scale_f32_16x16x128_f8f6f4(    \
    (a), (bfr), (c), 0, 0, 0, sA, 0, sB)

// One phase: ds-read A-quarter (and all B frags if LOADB), issue one half-tile
// stage, optional vmcnt checkpoint, barrier, lgkm drain, 8 MFMAs, barrier.
#define PHASE(q, b, LOADB, STAGE, WAITV) do {                                 \
    i32x8 _a0, _a1;                                                           \
    LDA_FRAG(_a0, 2 * (q), b);                                                \
    LDA_FRAG(_a1, 2 * (q) + 1, b);                                            \
    if (LOADB) {                                                              \
        LDB_FRAG(bf0, 0, b); LDB_FRAG(bf1, 1, b);                             \
        LDB_FRAG(bf2, 2, b); LDB_FRAG(bf3, 3, b);                             \
    }                                                                         \
    STAGE;                                                                    \
    WAITV;                                                                    \
    __builtin_amdgcn_s_barrier();                                             \
    asm volatile("s_waitcnt lgkmcnt(0)" ::: "memory");                        \
    __builtin_amdgcn_sched_barrier(0);                                        \
    __builtin_amdgcn_s_setprio(1);                                            \
    acc[2 * (q)][0]     = MFMA1(_a0, bf0, acc[2 * (q)][0]);                   \
    acc[2 * (q)][1]     = MFMA1(_a0, bf1, acc[2 * (q)][1]);                   \
    acc[2 * (q)][2]     = MFMA1(_a0, bf2, acc[2 * (q)][2]);                   \
    acc[2 * (q)][3]     = MFMA1(_a0, bf3, acc[2 * (q)][3]);                   \
    acc[2 * (q) + 1][0] = MFMA1(_a1, bf0, acc[2 * (q) + 1][0]);               \
    acc[2 * (q) + 1][1] = MFMA1(_a1, bf1, acc[2 * (q) + 1][1]);               \
    acc[2 * (q) + 1][2] = MFMA1(_a1, bf2, acc[2 * (q) + 1][2]);               \
    acc[2 * (q) + 1][3] = MFMA1(_a1, bf3, acc[2 * (q) + 1][3]);               \
    __builtin_amdgcn_s_setprio(0);                                            \
    __builtin_amdgcn_sched_barrier(0);                                        \
    __builtin_amdgcn_s_barrier();                                             \
    asm volatile("" ::: "memory");                                            \
} while (0)

__global__ __launch_bounds__(512, 1)
void gemm_lse_partial(const unsigned char* __restrict__ E,
                      const unsigned char* __restrict__ C,
                      const float* __restrict__ bias,
                      const int* __restrict__ targets,
                      float* __restrict__ row_sum,
                      float* __restrict__ tgt,
                      int N, int D, int V, int mtiles) {
    __shared__ unsigned char smem[131072];
    unsigned char* ldsA = smem;
    unsigned char* ldsB = smem + 65536;

    const int t_ = threadIdx.x;
    const int w  = t_ >> 6;
    const int l  = t_ & 63;
    const int quad = l >> 4;
    const int lm = l & 15;
    const int wr0 = (w >> 2) * 128;   // 2 row-groups of 128
    const int wc0 = (w & 3) * 64;     // 4 col-groups of 64
    const int c0 = ((quad << 1) ^ (lm & 7)) << 4;
    const int c1 = c0 ^ 16;

    // XCD-bijective block swizzle (nwg % 8 == 0 here; identity fallback else)
    const int nwg = (int)gridDim.x;
    int swz;
    if (nwg & 7) swz = (int)blockIdx.x;
    else         swz = ((int)blockIdx.x & 7) * (nwg >> 3) + ((int)blockIdx.x >> 3);
    const int mt = swz % mtiles;
    const int vt = swz / mtiles;
    const int m0 = mt * BM;
    const int v0 = vt * BN;

    // staging map: thread t -> row sr = t>>3, stored chunk t&7 (LDS linear per
    // wave: base + lane*16). Global chunk pre-swizzled: gc = (t&7) ^ (sr&7).
    const int sr = t_ >> 3;                    // 0..63
    const int gc = (t_ & 7) ^ (sr & 7);
    const unsigned char* gA = E + (size_t)(m0 + sr) * D + gc * 16;
    const unsigned char* gB = C + (size_t)(v0 + sr) * D + gc * 16;
    unsigned char* lA = ldsA + w * 1024;       // wave-uniform LDS base
    unsigned char* lB = ldsB + w * 1024;
    const size_t rowD64 = (size_t)64 * D;

    f32x4 acc[8][4] = {};
    i32x8 bf0, bf1, bf2, bf3;
    const int sA = 127;  // e8m0 2^0   (E)
    const int sB = 123;  // e8m0 2^-4  (undoes *16 in cast of C)
    const int KT  = D / BKB;   // 8 K-tiles
    const int NIT = KT / 2;    // 4 iterations, 2 K-tiles each

    // ---- prologue: K-tile 0 (A+B) into buf0, B of K-tile 1 into buf1 -------
    STG_A(0, 0, 0); STG_A(0, 1, 0);
    STG_B(0, 0, 0); STG_B(0, 1, 0);
    STG_B(1, 0, 1); STG_B(1, 1, 1);
    VM4;                                       // A(0),B(0) landed; B(1) in flight
    __builtin_amdgcn_s_barrier();
    asm volatile("" ::: "memory");

    // ---- main loop: iter t computes K-tiles 2t (buf0) and 2t+1 (buf1) ------
    // Stage stream: p1,2: A(2t+1); p3,4: B(2t+2); p5,6: A(2t+2); p7,8: B(2t+3).
    // Checkpoints vmcnt(4) at p4 (A(2t+1)+older landed) and p8 (A/B(2t+2)
    // landed). Last iter: only A(2t+1) staged; vmcnt(0) at p4.
    for (int t = 0; t < NIT; ++t) {
        const int k0 = 2 * t;
        const bool full = (t < NIT - 1);
        PHASE(0, 0, 1, STG_A(k0 + 1, 0, 1), NOPW);
        PHASE(1, 0, 0, STG_A(k0 + 1, 1, 1), NOPW);
        PHASE(2, 0, 0, if (full) STG_B(k0 + 2, 0, 0), NOPW);
        PHASE(3, 0, 0, if (full) STG_B(k0 + 2, 1, 0), if (full) VM4; else VM0);
        PHASE(0, 1, 1, if (full) STG_A(k0 + 2, 0, 0), NOPW);
        PHASE(1, 1, 0, if (full) STG_A(k0 + 2, 1, 0), NOPW);
        PHASE(2, 1, 0, if (full) STG_B(k0 + 3, 0, 1), NOPW);
        PHASE(3, 1, 0, if (full) STG_B(k0 + 3, 1, 1), if (full) VM4; else VM0);
    }

    // ---- epilogue: bias + exp + target extraction + per-row sums -----------
    // acc[ti][tj][r] -> row = wr0+ti*16+quad*4+r, col = wc0+tj*16+lm
    __syncthreads();                 // all MFMA/LDS done; re-alias tile LDS
    float* red = (float*)smem;       // [4 col-wave-groups][256 rows]

    float bv[4];
#pragma unroll
    for (int tj = 0; tj < 4; tj++) {
        int col = v0 + wc0 + tj * 16 + lm;
        bv[tj] = (col < V) ? bias[col] : -INFINITY;
    }
#pragma unroll
    for (int ti = 0; ti < 8; ti++) {
#pragma unroll
        for (int r = 0; r < 4; r++) {
            const int rl = wr0 + ti * 16 + quad * 4 + r;
            const int tl = targets[m0 + rl] - v0 - wc0;
            float s = 0.f;
#pragma unroll
            for (int tj = 0; tj < 4; tj++) {
                float v = acc[ti][tj][r] + bv[tj];   // pad col: exp(-inf)=0
                s += __expf(v);
                if (tj * 16 + lm == tl) tgt[m0 + rl] = v;
            }
#pragma unroll
            for (int off = 1; off < 16; off <<= 1)
                s += __shfl_xor(s, off, 64);
            if (lm == 0) red[(w & 3) * 256 + rl] = s;
        }
    }
    __syncthreads();
    if (t_ < 256)
        atomicAdd(&row_sum[m0 + t_],
                  red[t_] + red[256 + t_] + red[512 + t_] + red[768 + t_]);
}

// Finish: nll per row, block-reduce, atomic accumulate (sum, count).
__global__ void lse_finish(const float* __restrict__ row_sum,
                           const float* __restrict__ tgt,
                           const int* __restrict__ targets,
                           float* __restrict__ gacc, int N) {
    __shared__ float sred[8];
    int r = blockIdx.x * 256 + threadIdx.x;
    float nll = 0.f, cnt = 0.f;
    if (r < N) {
        int tg = targets[r];
        if (tg != -100) { nll = logf(row_sum[r]) - tgt[r]; cnt = 1.f; }
    }
#pragma unroll
    for (int off = 32; off; off >>= 1) {
        nll += __shfl_xor(nll, off, 64);
        cnt += __shfl_xor(cnt, off, 64);
    }
    int w = threadIdx.x >> 6, l = threadIdx.x & 63;
    if (l == 0) { sred[w] = nll; sred[4 + w] = cnt; }
    __syncthreads();
    if (threadIdx.x == 0) {
        atomicAdd(gacc, sred[0] + sred[1] + sred[2] + sred[3]);
        atomicAdd(gacc + 1, sred[4] + sred[5] + sred[6] + sred[7]);
    }
}

__global__ void final_scalar(const float* __restrict__ gacc, float* __restrict__ out) {
    out[0] = gacc[0] / fmaxf(gacc[1], 1.f);
}

extern "C" void kernel_launch(void* const* d_in, const int* in_sizes, int n_in,
                              void* d_out, int out_size, void* d_ws, size_t ws_size,
                              hipStream_t stream) {
    const float* e       = (const float*)d_in[0];
    const float* c       = (const float*)d_in[1];
    const int*   targets = (const int*)d_in[2];
    const float* bias    = (const float*)d_in[3];
    float* out = (float*)d_out;

    const int N = in_sizes[2];            // 8192
    const int V = in_sizes[3];            // 50257
    const int D = in_sizes[0] / N;        // 1024
    const int mtiles = N / BM;            // 32
    const int vtiles = (V + BN - 1) / BN; // 197
    const long Vpad = (long)vtiles * BN;  // 50432

    char* ws = (char*)d_ws;
    size_t off = 0;
    auto alloc = [&](size_t bytes) {
        void* p = ws + off;
        off += (bytes + 255) & ~(size_t)255;
        return p;
    };
    unsigned char* e_f8 = (unsigned char*)alloc((size_t)N * D);
    unsigned char* c_f8 = (unsigned char*)alloc((size_t)Vpad * D);
    float* row_sum = (float*)alloc((size_t)N * 4);   // zeroed below
    float* gacc    = (float*)alloc(8);               // adjacent to row_sum
    float* tgt     = (float*)alloc((size_t)N * 4);

    // one memset covers row_sum (N*4, 256-rounded) + gacc
    hipMemsetAsync(row_sum, 0, (size_t)N * 4 + 256 + 8, stream);

    const long ne  = (long)N * D;
    const long ncs = (long)V * D;
    const long ncd = Vpad * D;
    const long tot8 = (ne + ncd) / 8;
    cast_all_fp8<<<(int)((tot8 + 255) / 256), 256, 0, stream>>>(
        e, c, e_f8, c_f8, ne, ncs, ncd);

    const int nblk = mtiles * vtiles;     // 6304 (divisible by 8)
    gemm_lse_partial<<<nblk, 512, 0, stream>>>(e_f8, c_f8, bias, targets,
                                               row_sum, tgt, N, D, V, mtiles);

    lse_finish<<<(N + 255) / 256, 256, 0, stream>>>(row_sum, tgt, targets, gacc, N);
    final_scalar<<<1, 1, 0, stream>>>(gacc, out);
}

// Round 3
// 1097.757 us; speedup vs baseline: 2.7940x; 2.7847x over previous
//
#include <hip/hip_runtime.h>
#include <hip/hip_bf16.h>
#include <math.h>

// ---------------------------------------------------------------------------
// LinearCrossEntropy via MX-fp8 MFMA (16x16x128 f8f6f4, uniform HW scales).
// R7: register-feasible pipelined GEMM.
//   R5/R6 post-mortem: a 512-thread (8-wave) block is capped at 256 unified
//   VGPR+AGPR per wave (2048-reg CU pool / 8 waves) -- R5's 256x256 tile
//   needed ~315 live regs -> ~60-reg spill -> 5.7 GB scratch writes,
//   MfmaUtil 6%. No launch-bounds knob can lift a pool limit.
//   Fix: BM=128 x BN=256, 8 waves (2Mx4N), per-wave 64x64 output ->
//   acc 64 regs, total live ~160 < 240. 4-phase/2-K-tile schedule
//   (8 MFMA/phase), double-buffered 96 KB LDS, counted vmcnt(4), setprio,
//   XCD swizzle, fused LSE epilogue.
// Dispatches: memset, cast_all, gemm, lse_finish, final_scalar.
// ---------------------------------------------------------------------------

#define BM 128
#define BN 256
#define BKB 128  // K elements (= bytes, fp8) per K-tile

typedef int   i32x8 __attribute__((ext_vector_type(8)));
typedef float f32x4 __attribute__((ext_vector_type(4)));

__device__ __forceinline__ void load_lds16(const void* g, void* l) {
    __builtin_amdgcn_global_load_lds(
        (const __attribute__((address_space(1))) void*)g,
        (__attribute__((address_space(3))) void*)l, 16, 0, 0);
}

// ---- fp8 e4m3fn conversion -------------------------------------------------
__device__ __forceinline__ unsigned char f2e4m3_sw(float x) {
    unsigned u = __float_as_uint(x);
    unsigned s = (u >> 24) & 0x80;
    float ax = __uint_as_float(u & 0x7fffffff);
    if (ax != ax) return (unsigned char)(s | 0x7f);
    if (ax >= 448.f) return (unsigned char)(s | 0x7e);
    if (ax < 0.0009765625f) return (unsigned char)s;      // < 2^-10 -> 0
    if (ax < 0.015625f) {                                 // subnormal, ulp 2^-9
        int n = (int)rintf(ax * 512.f);
        return (unsigned char)(s | n);
    }
    int e = (int)((u >> 23) & 0xff) - 127;
    unsigned m = u & 0x7fffff;
    unsigned keep = m >> 20, rest = m & 0xfffff;
    if (rest > 0x80000u || (rest == 0x80000u && (keep & 1))) keep++;
    if (keep == 8) { keep = 0; e++; if (e > 8) return (unsigned char)(s | 0x7e); }
    return (unsigned char)(s | ((e + 7) << 3) | keep);
}

__device__ __forceinline__ unsigned int pk4_fp8(float a, float b, float c, float d) {
#if __has_builtin(__builtin_amdgcn_cvt_pk_fp8_f32)
    int v = __builtin_amdgcn_cvt_pk_fp8_f32(a, b, 0, false);  // bytes 0,1
    v = __builtin_amdgcn_cvt_pk_fp8_f32(c, d, v, true);       // bytes 2,3
    return (unsigned int)v;
#else
    return (unsigned int)f2e4m3_sw(a) | ((unsigned int)f2e4m3_sw(b) << 8) |
           ((unsigned int)f2e4m3_sw(c) << 16) | ((unsigned int)f2e4m3_sw(d) << 24);
#endif
}

// Combined cast: [0,ne) from e (scale 1), [ne, ne+ncd) from c (scale 16,
// zero-fill past ncs). All boundaries multiples of 8.
__global__ void cast_all_fp8(const float* __restrict__ e,
                             const float* __restrict__ c,
                             unsigned char* __restrict__ e_f8,
                             unsigned char* __restrict__ c_f8,
                             long ne, long ncs, long ncd) {
    long i8 = ((long)blockIdx.x * blockDim.x + threadIdx.x) * 8;
    if (i8 >= ne + ncd) return;
    const float* src;
    unsigned char* dst;
    float scale;
    bool zero = false;
    if (i8 < ne) {
        src = e + i8; dst = e_f8 + i8; scale = 1.0f;
    } else {
        long j8 = i8 - ne;
        dst = c_f8 + j8; scale = 16.0f;
        src = c + j8;
        zero = (j8 + 7 >= ncs);
    }
    uint2 o;
    if (!zero) {
        float4 v0 = *(const float4*)(src);
        float4 v1 = *(const float4*)(src + 4);
        o.x = pk4_fp8(v0.x * scale, v0.y * scale, v0.z * scale, v0.w * scale);
        o.y = pk4_fp8(v1.x * scale, v1.y * scale, v1.z * scale, v1.w * scale);
    } else {
        o.x = o.y = 0u;
    }
    *(uint2*)dst = o;
}

// ---- GEMM 128x256, 4-phase double-buffered pipeline, fused LSE epilogue ----
// E: [N][D] fp8, C: [Vpad][D] fp8 (zero-pad rows).
// LDS: A 2x(128x128B)=32KB at [0,32768), B 2x(256x128B)=64KB at [32768,98304).
// Row r chunk c (16B) stored at chunk position c^(r&7) (XOR swizzle), achieved
// by pre-swizzling the per-lane GLOBAL source address (linear LDS dest).
// Stage units: 512 thr x 16B = 8KB = 64 rows. A tile = 2 units, B = 4 units.
// Stream (iter t computes K-tiles 2t[buf0], 2t+1[buf1]):
//   P1: stage A(2t+1)->buf1 (2u); P2: stage B(2t+2)->buf0 (4u), VM4
//   P3: stage A(2t+2)->buf0 (2u); P4: stage B(2t+3)->buf1 (4u), VM4
// VM4@P2: kills [B(2t+1),A(2t+1)] needed by P3; leaves B(2t+2) in flight.
// VM4@P4: kills [A,B](2t+2) needed by next P1; leaves B(2t+3) in flight.

#define VM4 asm volatile("s_waitcnt vmcnt(4)" ::: "memory")
#define VM0 asm volatile("s_waitcnt vmcnt(0)" ::: "memory")
#define NOPW ((void)0)

// whole A K-tile (2 units)
#define STG_A(k, b) do {                                                      \
    const unsigned char* _s = gA + (size_t)(k) * 128;                         \
    load_lds16(_s,          lA + (b) * 16384);                                \
    load_lds16(_s + rowD64, lA + (b) * 16384 + 8192);                         \
} while (0)

// whole B K-tile (4 units)
#define STG_B(k, b) do {                                                      \
    const unsigned char* _s = gB + (size_t)(k) * 128;                         \
    load_lds16(_s,              lB + (b) * 32768);                            \
    load_lds16(_s + rowD64,     lB + (b) * 32768 + 8192);                     \
    load_lds16(_s + 2 * rowD64, lB + (b) * 32768 + 16384);                    \
    load_lds16(_s + 3 * rowD64, lB + (b) * 32768 + 24576);                    \
} while (0)

#define LDA_FRAG(dst, ti, b) do {                                             \
    const unsigned char* _pr = ldsA + (b) * 16384 + (wr0 + (ti) * 16 + lm) * 128; \
    int4 _lo = *(const int4*)(_pr + c0);                                      \
    int4 _hi = *(const int4*)(_pr + c1);                                      \
    dst = (i32x8){_lo.x, _lo.y, _lo.z, _lo.w, _hi.x, _hi.y, _hi.z, _hi.w};    \
} while (0)

#define LDB_FRAG(dst, tj, b) do {                                             \
    const unsigned char* _pr = ldsB + (b) * 32768 + (wc0 + (tj) * 16 + lm) * 128; \
    int4 _lo = *(const int4*)(_pr + c0);                                      \
    int4 _hi = *(const int4*)(_pr + c1);                                      \
    dst = (i32x8){_lo.x, _lo.y, _lo.z, _lo.w, _hi.x, _hi.y, _hi.z, _hi.w};    \
} while (0)

#define MFMA1(a, bfr, c) __builtin_amdgcn_mfma_scale_f32_16x16x128_f8f6f4(    \
    (a), (bfr), (c), 0, 0, 0, sA, 0, sB)

// One phase: ds-read 2 A-frags (and all 4 B frags if LOADB), issue stage,
// optional vmcnt checkpoint, barrier, lgkm drain, 8 MFMAs, barrier.
#define PHASE(q, b, LOADB, STAGE, WAITV) do {                                 \
    i32x8 _a0, _a1;                                                           \
    LDA_FRAG(_a0, 2 * (q), b);                                                \
    LDA_FRAG(_a1, 2 * (q) + 1, b);                                            \
    if (LOADB) {                                                              \
        LDB_FRAG(bf0, 0, b); LDB_FRAG(bf1, 1, b);                             \
        LDB_FRAG(bf2, 2, b); LDB_FRAG(bf3, 3, b);                             \
    }                                                                         \
    STAGE;                                                                    \
    WAITV;                                                                    \
    __builtin_amdgcn_s_barrier();                                             \
    asm volatile("s_waitcnt lgkmcnt(0)" ::: "memory");                        \
    __builtin_amdgcn_sched_barrier(0);                                        \
    __builtin_amdgcn_s_setprio(1);                                            \
    acc[2 * (q)][0]     = MFMA1(_a0, bf0, acc[2 * (q)][0]);                   \
    acc[2 * (q)][1]     = MFMA1(_a0, bf1, acc[2 * (q)][1]);                   \
    acc[2 * (q)][2]     = MFMA1(_a0, bf2, acc[2 * (q)][2]);                   \
    acc[2 * (q)][3]     = MFMA1(_a0, bf3, acc[2 * (q)][3]);                   \
    acc[2 * (q) + 1][0] = MFMA1(_a1, bf0, acc[2 * (q) + 1][0]);               \
    acc[2 * (q) + 1][1] = MFMA1(_a1, bf1, acc[2 * (q) + 1][1]);               \
    acc[2 * (q) + 1][2] = MFMA1(_a1, bf2, acc[2 * (q) + 1][2]);               \
    acc[2 * (q) + 1][3] = MFMA1(_a1, bf3, acc[2 * (q) + 1][3]);               \
    __builtin_amdgcn_s_setprio(0);                                            \
    __builtin_amdgcn_sched_barrier(0);                                        \
    __builtin_amdgcn_s_barrier();                                             \
    asm volatile("" ::: "memory");                                            \
} while (0)

__global__ __launch_bounds__(512)
void gemm_lse_partial(const unsigned char* __restrict__ E,
                      const unsigned char* __restrict__ C,
                      const float* __restrict__ bias,
                      const int* __restrict__ targets,
                      float* __restrict__ row_sum,
                      float* __restrict__ tgt,
                      int N, int D, int V, int mtiles) {
    __shared__ unsigned char smem[98304];
    unsigned char* ldsA = smem;             // 2 x 16 KB
    unsigned char* ldsB = smem + 32768;     // 2 x 32 KB

    const int t_ = threadIdx.x;
    const int w  = t_ >> 6;
    const int l  = t_ & 63;
    const int quad = l >> 4;
    const int lm = l & 15;
    const int wr0 = (w >> 2) * 64;    // 2 row-groups of 64 (BM=128)
    const int wc0 = (w & 3) * 64;     // 4 col-groups of 64 (BN=256)
    const int c0 = ((quad << 1) ^ (lm & 7)) << 4;
    const int c1 = c0 ^ 16;

    // XCD-bijective block swizzle (nwg % 8 == 0 here; identity fallback else)
    const int nwg = (int)gridDim.x;
    int swz;
    if (nwg & 7) swz = (int)blockIdx.x;
    else         swz = ((int)blockIdx.x & 7) * (nwg >> 3) + ((int)blockIdx.x >> 3);
    const int mt = swz % mtiles;
    const int vt = swz / mtiles;
    const int m0 = mt * BM;
    const int v0 = vt * BN;

    // staging map: thread t -> row sr = t>>3 (64 rows/unit), stored chunk t&7
    // (LDS linear per wave: base + lane*16). Global chunk pre-swizzled:
    // gc = (t&7) ^ (sr&7).
    const int sr = t_ >> 3;                    // 0..63
    const int gc = (t_ & 7) ^ (sr & 7);
    const unsigned char* gA = E + (size_t)(m0 + sr) * D + gc * 16;
    const unsigned char* gB = C + (size_t)(v0 + sr) * D + gc * 16;
    unsigned char* lA = ldsA + w * 1024;       // wave-uniform LDS base
    unsigned char* lB = ldsB + w * 1024;
    const size_t rowD64 = (size_t)64 * D;

    f32x4 acc[4][4] = {};
    i32x8 bf0, bf1, bf2, bf3;
    const int sA = 127;  // e8m0 2^0   (E)
    const int sB = 123;  // e8m0 2^-4  (undoes *16 in cast of C)
    const int KT  = D / BKB;   // 8 K-tiles
    const int NIT = KT / 2;    // 4 iterations, 2 K-tiles each

    // ---- prologue: K-tile 0 (A+B) into buf0, B of K-tile 1 into buf1 -------
    STG_A(0, 0);
    STG_B(0, 0);
    STG_B(1, 1);
    VM4;                                       // A(0),B(0) landed; B(1) in flight
    __builtin_amdgcn_s_barrier();
    asm volatile("" ::: "memory");

    // ---- main loop ---------------------------------------------------------
    for (int it = 0; it < NIT; ++it) {
        const int k0 = 2 * it;
        const bool full = (it < NIT - 1);
        PHASE(0, 0, 1, STG_A(k0 + 1, 1), NOPW);
        PHASE(1, 0, 0, if (full) STG_B(k0 + 2, 0), if (full) VM4; else VM0);
        PHASE(0, 1, 1, if (full) STG_A(k0 + 2, 0), NOPW);
        PHASE(1, 1, 0, if (full) STG_B(k0 + 3, 1), if (full) VM4; else VM0);
    }

    // ---- epilogue: bias + exp + target extraction + per-row sums -----------
    // acc[ti][tj][r] -> row = wr0+ti*16+quad*4+r (of 128),
    //                   col = wc0+tj*16+lm (of 256)
    __syncthreads();                 // all MFMA/LDS done; re-alias tile LDS
    float* red = (float*)smem;       // [4 col-wave-groups][128 rows]

    float bv[4];
#pragma unroll
    for (int tj = 0; tj < 4; tj++) {
        int col = v0 + wc0 + tj * 16 + lm;
        bv[tj] = (col < V) ? bias[col] : -INFINITY;
    }
#pragma unroll
    for (int ti = 0; ti < 4; ti++) {
#pragma unroll
        for (int r = 0; r < 4; r++) {
            const int rl = wr0 + ti * 16 + quad * 4 + r;
            const int tl = targets[m0 + rl] - v0 - wc0;
            float s = 0.f;
#pragma unroll
            for (int tj = 0; tj < 4; tj++) {
                float v = acc[ti][tj][r] + bv[tj];   // pad col: exp(-inf)=0
                s += __expf(v);
                if (tj * 16 + lm == tl) tgt[m0 + rl] = v;
            }
#pragma unroll
            for (int off = 1; off < 16; off <<= 1)
                s += __shfl_xor(s, off, 64);
            if (lm == 0) red[(w & 3) * 128 + rl] = s;
        }
    }
    __syncthreads();
    if (t_ < BM)
        atomicAdd(&row_sum[m0 + t_],
                  red[t_] + red[128 + t_] + red[256 + t_] + red[384 + t_]);
}

// Finish: nll per row, block-reduce, atomic accumulate (sum, count).
__global__ void lse_finish(const float* __restrict__ row_sum,
                           const float* __restrict__ tgt,
                           const int* __restrict__ targets,
                           float* __restrict__ gacc, int N) {
    __shared__ float sred[8];
    int r = blockIdx.x * 256 + threadIdx.x;
    float nll = 0.f, cnt = 0.f;
    if (r < N) {
        int tg = targets[r];
        if (tg != -100) { nll = logf(row_sum[r]) - tgt[r]; cnt = 1.f; }
    }
#pragma unroll
    for (int off = 32; off; off >>= 1) {
        nll += __shfl_xor(nll, off, 64);
        cnt += __shfl_xor(cnt, off, 64);
    }
    int w = threadIdx.x >> 6, l = threadIdx.x & 63;
    if (l == 0) { sred[w] = nll; sred[4 + w] = cnt; }
    __syncthreads();
    if (threadIdx.x == 0) {
        atomicAdd(gacc, sred[0] + sred[1] + sred[2] + sred[3]);
        atomicAdd(gacc + 1, sred[4] + sred[5] + sred[6] + sred[7]);
    }
}

__global__ void final_scalar(const float* __restrict__ gacc, float* __restrict__ out) {
    out[0] = gacc[0] / fmaxf(gacc[1], 1.f);
}

extern "C" void kernel_launch(void* const* d_in, const int* in_sizes, int n_in,
                              void* d_out, int out_size, void* d_ws, size_t ws_size,
                              hipStream_t stream) {
    const float* e       = (const float*)d_in[0];
    const float* c       = (const float*)d_in[1];
    const int*   targets = (const int*)d_in[2];
    const float* bias    = (const float*)d_in[3];
    float* out = (float*)d_out;

    const int N = in_sizes[2];            // 8192
    const int V = in_sizes[3];            // 50257
    const int D = in_sizes[0] / N;        // 1024
    const int mtiles = N / BM;            // 64
    const int vtiles = (V + BN - 1) / BN; // 197
    const long Vpad = (long)vtiles * BN;  // 50432

    char* ws = (char*)d_ws;
    size_t off = 0;
    auto alloc = [&](size_t bytes) {
        void* p = ws + off;
        off += (bytes + 255) & ~(size_t)255;
        return p;
    };
    unsigned char* e_f8 = (unsigned char*)alloc((size_t)N * D);
    unsigned char* c_f8 = (unsigned char*)alloc((size_t)Vpad * D);
    float* row_sum = (float*)alloc((size_t)N * 4);   // zeroed below
    float* gacc    = (float*)alloc(8);               // adjacent to row_sum
    float* tgt     = (float*)alloc((size_t)N * 4);

    // one memset covers row_sum (N*4, 256-rounded) + gacc
    hipMemsetAsync(row_sum, 0, (size_t)N * 4 + 256 + 8, stream);

    const long ne  = (long)N * D;
    const long ncs = (long)V * D;
    const long ncd = Vpad * D;
    const long tot8 = (ne + ncd) / 8;
    cast_all_fp8<<<(int)((tot8 + 255) / 256), 256, 0, stream>>>(
        e, c, e_f8, c_f8, ne, ncs, ncd);

    const int nblk = mtiles * vtiles;     // 12608 (divisible by 8)
    gemm_lse_partial<<<nblk, 512, 0, stream>>>(e_f8, c_f8, bias, targets,
                                               row_sum, tgt, N, D, V, mtiles);

    lse_finish<<<(N + 255) / 256, 256, 0, stream>>>(row_sum, tgt, targets, gacc, N);
    final_scalar<<<1, 1, 0, stream>>>(gacc, out);
}